// Round 1
// baseline (179.329 us; speedup 1.0000x reference)
//
#include <hip/hip_runtime.h>
#include <hip/hip_bf16.h>

typedef unsigned short u16;
typedef __bf16 bf16x8 __attribute__((ext_vector_type(8)));
typedef float f32x4 __attribute__((ext_vector_type(4)));

typedef const __attribute__((address_space(1))) void gv_t;
typedef __attribute__((address_space(3))) void lv_t;

#define NN 2048
#define DD 1024
#define SS 49
#define CC 1000
#define CP 1024   // C padded to multiple of 128

__device__ inline u16 f2bf(float f) {
    __hip_bfloat16 h = __float2bfloat16(f);
    union { __hip_bfloat16 h; u16 u; } cv; cv.h = h; return cv.u;
}

// ---------------- pooling: z[n,d] = mean_s x[n,d,s]; also emit bf16 copy ----
// 256 rows (n,d pairs) per block; rows are contiguous 49-float segments, so a
// block covers a contiguous 12544-float region. Stage to LDS with coalesced
// float4 loads, then each thread reduces its own row (stride 49 is odd ->
// 2-way LDS bank aliasing only, which is free).
__global__ __launch_bounds__(256) void pool_k(const float* __restrict__ x,
                                              float* __restrict__ zf,
                                              u16* __restrict__ zb) {
    __shared__ float lds[256 * SS];            // 50176 B
    const int tid = threadIdx.x;
    const size_t base = (size_t)blockIdx.x * (256 * SS);
    const float4* src = (const float4*)(x + base);
    float4* dst = (float4*)lds;
    #pragma unroll
    for (int i = 0; i < 13; i++) {
        int idx = i * 256 + tid;
        if (idx < (256 * SS) / 4) dst[idx] = src[idx];
    }
    __syncthreads();
    const float* r = lds + tid * SS;
    float s = 0.f;
    #pragma unroll
    for (int j = 0; j < SS; j++) s += r[j];
    s *= (1.f / (float)SS);
    size_t o = (size_t)blockIdx.x * 256 + tid;
    zf[o] = s;
    zb[o] = f2bf(s);
}

// ---------------- prep: Q = bf16(P + P^T); mu_bf16 zero-padded to CP rows ---
__global__ __launch_bounds__(256) void prep_q(const float* __restrict__ P,
                                              u16* __restrict__ q) {
    int i = blockIdx.x * 256 + threadIdx.x;      // over DD*DD
    int r = i >> 10, c = i & 1023;
    q[i] = f2bf(P[i] + P[c * DD + r]);
}

__global__ __launch_bounds__(256) void prep_mu(const float* __restrict__ mu,
                                               u16* __restrict__ mb) {
    int i = blockIdx.x * 256 + threadIdx.x;      // over CP*DD
    int c = i >> 10;
    mb[i] = f2bf(c < CC ? mu[i] : 0.f);
}

// ---------------- row dot: out[row] = scale * dot(a[row,:], b[row,:]) -------
__global__ __launch_bounds__(256) void rowdot(const float* __restrict__ a,
                                              const float* __restrict__ b,
                                              float* __restrict__ out, float scale) {
    const int row = blockIdx.x, tid = threadIdx.x;
    const float4* a4 = (const float4*)(a + (size_t)row * DD);
    const float4* b4 = (const float4*)(b + (size_t)row * DD);
    float4 av = a4[tid], bv = b4[tid];
    float p = av.x * bv.x + av.y * bv.y + av.z * bv.z + av.w * bv.w;
    #pragma unroll
    for (int off = 32; off; off >>= 1) p += __shfl_down(p, off);
    __shared__ float red[4];
    if ((tid & 63) == 0) red[tid >> 6] = p;
    __syncthreads();
    if (tid == 0) out[row] = scale * (red[0] + red[1] + red[2] + red[3]);
}

// ---------------- bf16 MFMA GEMM: C[M,N] = A[M,K] x Bt[N,K]^T ---------------
// m97 structure: 128x128 tile, BK=32, 4 waves each computing 64x64 via 4x4
// grid of 16x16x32 MFMA fragments; global_load_lds width=16 staging.
// MODE 0: write f32 C and bf16 C.   MODE 1: write f32 C only.
// MODE 2: score epilogue -> So[m*cvalid+n] = 0.5*acc - qzh[m] - qmuh[n], n<cvalid.
#define BM 128
#define BN 128
#define BK 32

template <int MODE>
__global__ __launch_bounds__(256) void gemm_bt(const u16* __restrict__ A,
                                               const u16* __restrict__ Bt,
                                               int N, int K, int nbn,
                                               float* __restrict__ Cf,
                                               u16* __restrict__ Cb,
                                               const float* __restrict__ qzh,
                                               const float* __restrict__ qmuh,
                                               float* __restrict__ So, int cvalid) {
    __shared__ char As[BM * BK * 2];   // 8 KiB
    __shared__ char Bs[BN * BK * 2];   // 8 KiB
    const int tid = threadIdx.x;
    const int bm = blockIdx.x / nbn, bn = blockIdx.x % nbn;
    const int m0 = bm * BM, n0 = bn * BN;
    const int lane = tid & 63, w = tid >> 6;
    const int wr = w >> 1, wc = w & 1;
    const int r16 = lane & 15, hk = lane >> 4;

    f32x4 acc[4][4] = {};

    const char* Ab = (const char*)A;
    const char* Bb = (const char*)Bt;
    const int c0 = tid, c1 = 256 + tid;
    const int rA0 = c0 >> 2, cb0 = (c0 & 3) << 4;
    const int rA1 = c1 >> 2, cb1 = (c1 & 3) << 4;

    for (int k0 = 0; k0 < K; k0 += BK) {
        __builtin_amdgcn_global_load_lds((gv_t*)(Ab + ((size_t)(m0 + rA0) * K + k0) * 2 + cb0),
                                         (lv_t*)(As + c0 * 16), 16, 0, 0);
        __builtin_amdgcn_global_load_lds((gv_t*)(Ab + ((size_t)(m0 + rA1) * K + k0) * 2 + cb1),
                                         (lv_t*)(As + c1 * 16), 16, 0, 0);
        __builtin_amdgcn_global_load_lds((gv_t*)(Bb + ((size_t)(n0 + rA0) * K + k0) * 2 + cb0),
                                         (lv_t*)(Bs + c0 * 16), 16, 0, 0);
        __builtin_amdgcn_global_load_lds((gv_t*)(Bb + ((size_t)(n0 + rA1) * K + k0) * 2 + cb1),
                                         (lv_t*)(Bs + c1 * 16), 16, 0, 0);
        __syncthreads();   // drains vmcnt before LDS reads

        bf16x8 a[4], b[4];
        #pragma unroll
        for (int mi = 0; mi < 4; mi++)
            a[mi] = *(const bf16x8*)(As + ((wr * 64 + mi * 16 + r16) * (BK * 2) + hk * 16));
        #pragma unroll
        for (int ni = 0; ni < 4; ni++)
            b[ni] = *(const bf16x8*)(Bs + ((wc * 64 + ni * 16 + r16) * (BK * 2) + hk * 16));
        #pragma unroll
        for (int mi = 0; mi < 4; mi++)
            #pragma unroll
            for (int ni = 0; ni < 4; ni++)
                acc[mi][ni] = __builtin_amdgcn_mfma_f32_16x16x32_bf16(a[mi], b[ni], acc[mi][ni], 0, 0, 0);
        __syncthreads();   // all waves done reading before next stage
    }

    // epilogue: C/D layout col=lane&15, row=(lane>>4)*4+r  [verified m89/m91]
    const int cr = (lane >> 4) * 4, cc = lane & 15;
    #pragma unroll
    for (int mi = 0; mi < 4; mi++) {
        #pragma unroll
        for (int ni = 0; ni < 4; ni++) {
            const int gr = m0 + wr * 64 + mi * 16 + cr;
            const int gc = n0 + wc * 64 + ni * 16 + cc;
            if (MODE == 2) {
                if (gc < cvalid) {
                    float qm = qmuh[gc];
                    #pragma unroll
                    for (int r = 0; r < 4; r++)
                        So[(size_t)(gr + r) * cvalid + gc] =
                            0.5f * acc[mi][ni][r] - qzh[gr + r] - qm;
                }
            } else {
                #pragma unroll
                for (int r = 0; r < 4; r++) {
                    float v = acc[mi][ni][r];
                    Cf[(size_t)(gr + r) * N + gc] = v;
                    if (MODE == 0) Cb[(size_t)(gr + r) * N + gc] = f2bf(v);
                }
            }
        }
    }
}

extern "C" void kernel_launch(void* const* d_in, const int* in_sizes, int n_in,
                              void* d_out, int out_size, void* d_ws, size_t ws_size,
                              hipStream_t stream) {
    const float* x  = (const float*)d_in[0];   // [N, D, S]
    const float* mu = (const float*)d_in[1];   // [C, D]
    const float* P  = (const float*)d_in[2];   // [D, D]
    float* out = (float*)d_out;                // [N, C]

    // workspace carve (all offsets multiples of 4096; total ~31.5 MB)
    char* w = (char*)d_ws;
    float* z_f32 = (float*)w;  w += (size_t)NN * DD * 4;
    u16*   z_bf  = (u16*)w;    w += (size_t)NN * DD * 2;
    u16*   mu_bf = (u16*)w;    w += (size_t)CP * DD * 2;
    u16*   q_bf  = (u16*)w;    w += (size_t)DD * DD * 2;
    float* b_f32 = (float*)w;  w += (size_t)CP * DD * 4;
    u16*   b_bf  = (u16*)w;    w += (size_t)CP * DD * 2;
    float* zq    = (float*)w;  w += (size_t)NN * DD * 4;
    float* qzh   = (float*)w;  w += (size_t)NN * 4;
    float* qmuh  = (float*)w;  /* CP*4 */

    // 1) pooling: z (f32 + bf16)
    pool_k<<<(NN * DD) / 256, 256, 0, stream>>>(x, z_f32, z_bf);
    // 2) Q = bf16(P+P^T); mu -> bf16 (zero-padded rows 1000..1023)
    prep_q<<<(DD * DD) / 256, 256, 0, stream>>>(P, q_bf);
    prep_mu<<<(CP * DD) / 256, 256, 0, stream>>>(mu, mu_bf);
    // 3) B[c,d] = mu_c . Q_d  (Q symmetric)  -> f32 + bf16
    gemm_bt<0><<<(CP / BM) * (DD / BN), 256, 0, stream>>>(
        mu_bf, q_bf, DD, DD, DD / BN, b_f32, b_bf, nullptr, nullptr, nullptr, 0);
    // 4) zQ[n,d] = z_n . Q_d -> f32
    gemm_bt<1><<<(NN / BM) * (DD / BN), 256, 0, stream>>>(
        z_bf, q_bf, DD, DD, DD / BN, zq, nullptr, nullptr, nullptr, nullptr, 0);
    // 5) qzh[n] = 0.25 * dot(zQ[n], z[n]) = 0.5 z P z ; qmuh[c] = 0.5 mu P mu
    rowdot<<<NN, 256, 0, stream>>>(zq, z_f32, qzh, 0.25f);
    rowdot<<<CC, 256, 0, stream>>>(b_f32, mu, qmuh, 0.25f);
    // 6) score[n,c] = 0.5 * (z_n . B_c) - qzh[n] - qmuh[c]  -> d_out
    gemm_bt<2><<<(NN / BM) * (CP / BN), 256, 0, stream>>>(
        z_bf, b_bf, CP, DD, CP / BN, nullptr, nullptr, qzh, qmuh, out, CC);
}

// Round 2
// 154.134 us; speedup vs baseline: 1.1635x; 1.1635x over previous
//
#include <hip/hip_runtime.h>
#include <hip/hip_bf16.h>

typedef unsigned short u16;
typedef __bf16 bf16x8 __attribute__((ext_vector_type(8)));
typedef float f32x4 __attribute__((ext_vector_type(4)));

typedef const __attribute__((address_space(1))) void gv_t;
typedef __attribute__((address_space(3))) void lv_t;

#define NN 2048
#define DD 1024
#define SS 49
#define CC 1000
#define CP 1024   // C padded to multiple of 128

__device__ inline u16 f2bf(float f) {
    __hip_bfloat16 h = __float2bfloat16(f);
    union { __hip_bfloat16 h; u16 u; } cv; cv.h = h; return cv.u;
}

// ---------------- pooling: z[n,d] = mean_s x[n,d,s]; f32 + bf16 outputs -----
// 256 rows (49 floats each) per block = contiguous 50176 B region. Stage to
// LDS with coalesced float4 loads; each thread reduces its own row (stride 49
// odd -> only 2-way LDS bank aliasing, which is free).
__global__ __launch_bounds__(256) void pool_k(const float* __restrict__ x,
                                              float* __restrict__ zf,
                                              u16* __restrict__ zb) {
    __shared__ float lds[256 * SS];            // 50176 B
    const int tid = threadIdx.x;
    const size_t base = (size_t)blockIdx.x * (256 * SS);
    const float4* src = (const float4*)(x + base);
    float4* dst = (float4*)lds;
    #pragma unroll
    for (int i = 0; i < 13; i++) {
        int idx = i * 256 + tid;
        if (idx < (256 * SS) / 4) dst[idx] = src[idx];
    }
    __syncthreads();
    const float* r = lds + tid * SS;
    float s = 0.f;
    #pragma unroll
    for (int j = 0; j < SS; j++) s += r[j];
    s *= (1.f / (float)SS);
    size_t o = (size_t)blockIdx.x * 256 + tid;
    zf[o] = s;
    zb[o] = f2bf(s);
}

// -------- prep: Q = bf16(P+P^T); ab rows 0..CP-1 = bf16(mu) zero-padded; ----
// -------- also zero the qzh/qmuh atomic accumulators. ----------------------
__global__ __launch_bounds__(256) void prep_all(const float* __restrict__ P,
                                                const float* __restrict__ mu,
                                                u16* __restrict__ q,
                                                u16* __restrict__ ab,
                                                float* __restrict__ qzh,
                                                float* __restrict__ qmuh) {
    int i = blockIdx.x * 256 + threadIdx.x;      // 0 .. DD*DD-1 (== CP*DD)
    int r = i >> 10, c = i & 1023;
    q[i]  = f2bf(P[i] + P[c * DD + r]);
    ab[i] = f2bf(r < CC ? mu[i] : 0.f);
    if (i < NN) qzh[i]  = 0.f;
    if (i < CP) qmuh[i] = 0.f;
}

// ---------------- bf16 MFMA GEMM: C[M,N] = A[M,K] x Bt[N,K]^T ---------------
// m97 structure + 2-phase double-buffered K-loop (T3 minimal recipe): issue
// next tile's global_load_lds BEFORE ds_read+MFMA of current tile, single
// barrier per tile. At ~1 block/CU there is no cross-block TLP, so this
// prefetch is what hides HBM/L2 latency.
// MODE 3 (stacked [mu;z] x Q): rows<CP write b_bf and atomically accumulate
//   qmuh[c] += 0.25*sum_d B[c,d]*mu[c,d]; rows>=CP write nothing and
//   accumulate qzh[n] += 0.25*sum_d (zQ)[n,d]*z[n,d].
// MODE 2 (score): out[m*cvalid+n] = 0.5*acc - qzh[m] - qmuh[n], n<cvalid.
#define BM 128
#define BN 128
#define BK 32

template <int MODE>
__global__ __launch_bounds__(256) void gemm_bt(const u16* __restrict__ A,
                                               const u16* __restrict__ Bt,
                                               int N, int K, int nbn,
                                               u16* __restrict__ Cb,
                                               const float* __restrict__ muf,
                                               const float* __restrict__ zf,
                                               float* __restrict__ qmuh_w,
                                               float* __restrict__ qzh_w,
                                               const float* __restrict__ qzr,
                                               const float* __restrict__ qmr,
                                               float* __restrict__ So, int cvalid) {
    __shared__ char As[2][BM * BK * 2];   // 2 x 8 KiB
    __shared__ char Bs[2][BN * BK * 2];   // 2 x 8 KiB
    const int tid = threadIdx.x;
    const int bm = blockIdx.x / nbn, bn = blockIdx.x % nbn;
    const int m0 = bm * BM, n0 = bn * BN;
    const int lane = tid & 63, w = tid >> 6;
    const int wr = w >> 1, wc = w & 1;
    const int r16 = lane & 15, hk = lane >> 4;

    f32x4 acc[4][4] = {};

    const char* Ab = (const char*)A;
    const char* Bb = (const char*)Bt;
    const int c0 = tid, c1 = 256 + tid;
    const int rA0 = c0 >> 2, cb0 = (c0 & 3) << 4;
    const int rA1 = c1 >> 2, cb1 = (c1 & 3) << 4;

    auto stage = [&](int buf, int k0) {
        __builtin_amdgcn_global_load_lds((gv_t*)(Ab + ((size_t)(m0 + rA0) * K + k0) * 2 + cb0),
                                         (lv_t*)(As[buf] + c0 * 16), 16, 0, 0);
        __builtin_amdgcn_global_load_lds((gv_t*)(Ab + ((size_t)(m0 + rA1) * K + k0) * 2 + cb1),
                                         (lv_t*)(As[buf] + c1 * 16), 16, 0, 0);
        __builtin_amdgcn_global_load_lds((gv_t*)(Bb + ((size_t)(n0 + rA0) * K + k0) * 2 + cb0),
                                         (lv_t*)(Bs[buf] + c0 * 16), 16, 0, 0);
        __builtin_amdgcn_global_load_lds((gv_t*)(Bb + ((size_t)(n0 + rA1) * K + k0) * 2 + cb1),
                                         (lv_t*)(Bs[buf] + c1 * 16), 16, 0, 0);
    };

    const int nt = K / BK;
    stage(0, 0);
    __syncthreads();                 // drain prologue loads
    int cur = 0;
    for (int t = 0; t < nt; ++t) {
        if (t + 1 < nt) stage(cur ^ 1, (t + 1) * BK);   // prefetch next tile
        bf16x8 a[4], b[4];
        #pragma unroll
        for (int mi = 0; mi < 4; mi++)
            a[mi] = *(const bf16x8*)(As[cur] + ((wr * 64 + mi * 16 + r16) * (BK * 2) + hk * 16));
        #pragma unroll
        for (int ni = 0; ni < 4; ni++)
            b[ni] = *(const bf16x8*)(Bs[cur] + ((wc * 64 + ni * 16 + r16) * (BK * 2) + hk * 16));
        #pragma unroll
        for (int mi = 0; mi < 4; mi++)
            #pragma unroll
            for (int ni = 0; ni < 4; ni++)
                acc[mi][ni] = __builtin_amdgcn_mfma_f32_16x16x32_bf16(a[mi], b[ni], acc[mi][ni], 0, 0, 0);
        __syncthreads();             // prefetch landed + all reads of cur done
        cur ^= 1;
    }

    // epilogue: C/D layout col=lane&15, row=(lane>>4)*4+r  [verified m89/m91]
    const int cr = (lane >> 4) * 4, cc = lane & 15;
    if (MODE == 2) {
        #pragma unroll
        for (int mi = 0; mi < 4; mi++) {
            #pragma unroll
            for (int ni = 0; ni < 4; ni++) {
                const int gr = m0 + wr * 64 + mi * 16 + cr;
                const int gc = n0 + wc * 64 + ni * 16 + cc;
                if (gc < cvalid) {
                    float qm = qmr[gc];
                    #pragma unroll
                    for (int r = 0; r < 4; r++)
                        So[(size_t)(gr + r) * cvalid + gc] =
                            0.5f * acc[mi][ni][r] - qzr[gr + r] - qm;
                }
            }
        }
    } else {  // MODE 3
        #pragma unroll
        for (int mi = 0; mi < 4; mi++) {
            const int gr0 = m0 + wr * 64 + mi * 16 + cr;      // block-uniform side
            const bool isMu = (gr0 < CP);                     // uniform per block
            const float* S = isMu ? muf : zf;
            float* dst = isMu ? qmuh_w : qzh_w;
            const int rbase = isMu ? gr0 : gr0 - CP;
            #pragma unroll
            for (int r = 0; r < 4; r++) {
                const int row = rbase + r;
                float v = 0.f;
                #pragma unroll
                for (int ni = 0; ni < 4; ni++) {
                    const int gc = n0 + wc * 64 + ni * 16 + cc;
                    float a = acc[mi][ni][r];
                    v += a * S[(size_t)row * DD + gc];
                    if (isMu) Cb[(size_t)(gr0 + r) * N + gc] = f2bf(a);
                }
                #pragma unroll
                for (int m = 1; m < 16; m <<= 1) v += __shfl_xor(v, m);
                if ((lane & 15) == 0) atomicAdd(dst + row, 0.25f * v);
            }
        }
    }
}

extern "C" void kernel_launch(void* const* d_in, const int* in_sizes, int n_in,
                              void* d_out, int out_size, void* d_ws, size_t ws_size,
                              hipStream_t stream) {
    const float* x  = (const float*)d_in[0];   // [N, D, S]
    const float* mu = (const float*)d_in[1];   // [C, D]
    const float* P  = (const float*)d_in[2];   // [D, D]
    float* out = (float*)d_out;                // [N, C]

    // workspace carve (~18.5 MB)
    char* w = (char*)d_ws;
    u16*   ab    = (u16*)w;    w += (size_t)(CP + NN) * DD * 2;  // [mu_bf ; z_bf]
    u16*   q_bf  = (u16*)w;    w += (size_t)DD * DD * 2;
    u16*   b_bf  = (u16*)w;    w += (size_t)CP * DD * 2;
    float* z_f32 = (float*)w;  w += (size_t)NN * DD * 4;
    float* qzh   = (float*)w;  w += (size_t)NN * 4;
    float* qmuh  = (float*)w;  /* CP*4 */

    u16* z_bf = ab + (size_t)CP * DD;

    // 1) prep: Q=bf16(P+P^T), ab[0:CP)=bf16(mu) padded, zero qzh/qmuh
    prep_all<<<(DD * DD) / 256, 256, 0, stream>>>(P, mu, q_bf, ab, qzh, qmuh);
    // 2) pooling: z (f32 + bf16 into ab rows CP..CP+NN)
    pool_k<<<(NN * DD) / 256, 256, 0, stream>>>(x, z_f32, z_bf);
    // 3) stacked GEMM: [mu;z] x Q -> B rows write b_bf + qmuh atomics;
    //    z rows accumulate qzh atomics only (zQ never stored)
    gemm_bt<3><<<((CP + NN) / BM) * (DD / BN), 256, 0, stream>>>(
        ab, q_bf, DD, DD, DD / BN, b_bf, mu, z_f32, qmuh, qzh,
        nullptr, nullptr, nullptr, 0);
    // 4) score GEMM: z x B^T with epilogue 0.5*acc - qzh[n] - qmuh[c] -> d_out
    gemm_bt<2><<<(NN / BM) * (CP / BN), 256, 0, stream>>>(
        z_bf, b_bf, CP, DD, CP / BN, nullptr, nullptr, nullptr, nullptr, nullptr,
        qzh, qmuh, out, CC);
}

// Round 3
// 124.185 us; speedup vs baseline: 1.4441x; 1.2412x over previous
//
#include <hip/hip_runtime.h>
#include <hip/hip_bf16.h>

typedef unsigned short u16;
typedef __bf16 bf16x8 __attribute__((ext_vector_type(8)));
typedef float f32x4 __attribute__((ext_vector_type(4)));

typedef const __attribute__((address_space(1))) void gv_t;
typedef __attribute__((address_space(3))) void lv_t;

#define NN 2048
#define DD 1024
#define SS 49
#define CC 1000
#define CP 1024   // C padded to multiple of 64

#define POOL_BLOCKS ((NN * DD) / 256)   // 8192
#define PREP_BLOCKS ((DD * DD) / 256)   // 4096

__device__ inline u16 f2bf(float f) {
    __hip_bfloat16 h = __float2bfloat16(f);
    union { __hip_bfloat16 h; u16 u; } cv; cv.h = h; return cv.u;
}

// ------- fused pool + prep ------------------------------------------------
// blocks [0, POOL_BLOCKS): z[n,d] = mean_s x[n,d,s] -> z_f32 + z_bf(ab rows CP..)
//   256 rows (49 floats) per block = contiguous 50176B; LDS-stage with
//   coalesced float4, per-thread row reduce (stride 49 odd -> 2-way alias, free).
// blocks [POOL_BLOCKS, +PREP_BLOCKS): Q = bf16(P+P^T); ab rows 0..CP-1 =
//   bf16(mu) (mu rows CC..CP-1 zero); zero qzh/qmuh atomic accumulators.
// prep traffic (~16MB) hides in the BW shadow of pool's 411MB stream.
__global__ __launch_bounds__(256) void pool_prep_k(const float* __restrict__ x,
                                                   const float* __restrict__ P,
                                                   const float* __restrict__ mu,
                                                   float* __restrict__ zf,
                                                   u16* __restrict__ zb,
                                                   u16* __restrict__ q,
                                                   u16* __restrict__ ab,
                                                   float* __restrict__ qzh,
                                                   float* __restrict__ qmuh) {
    __shared__ float lds[256 * SS];            // 50176 B
    const int tid = threadIdx.x;
    if (blockIdx.x < POOL_BLOCKS) {
        const size_t base = (size_t)blockIdx.x * (256 * SS);
        const float4* src = (const float4*)(x + base);
        float4* dst = (float4*)lds;
        #pragma unroll
        for (int i = 0; i < 13; i++) {
            int idx = i * 256 + tid;
            if (idx < (256 * SS) / 4) dst[idx] = src[idx];
        }
        __syncthreads();
        const float* r = lds + tid * SS;
        float s = 0.f;
        #pragma unroll
        for (int j = 0; j < SS; j++) s += r[j];
        s *= (1.f / (float)SS);
        size_t o = (size_t)blockIdx.x * 256 + tid;
        zf[o] = s;
        zb[o] = f2bf(s);
    } else {
        int i = (blockIdx.x - POOL_BLOCKS) * 256 + tid;   // 0 .. DD*DD-1
        int r = i >> 10, c = i & 1023;
        q[i]  = f2bf(P[i] + P[c * DD + r]);
        ab[i] = f2bf(r < CC ? mu[i] : 0.f);
        if (i < NN) qzh[i]  = 0.f;
        if (i < CP) qmuh[i] = 0.f;
    }
}

// ------- bf16 MFMA GEMM: C[M,N] = A[M,K] x Bt[N,K]^T ------------------------
// 64x64 tile, BK=64, 4 waves (2x2), each wave a 32x32 output (2x2 frags of
// 16x16x32). Rationale: grids here are 512-768 blocks -> 2-3 blocks/CU of
// TLP (the 128^2 tile gave <1 block/CU, fully latency-exposed). 2-phase
// double-buffer; LDS rows are 128B so ds_read_b128 would serialize 2x ->
// XOR-swizzle slots via pre-swizzled GLOBAL source (linear LDS dest, rule
// "both-sides-or-neither") + same XOR on the read side. LDS 32KB/block.
// MODE 3 (stacked [mu;z] x Q): mu-rows write b_bf and atomic-accumulate
//   qmuh[c] += 0.25*B[c,:].mu[c,:]; z-rows accumulate qzh[n] += 0.25*(zQ).z.
// MODE 2 (score): out[m*cvalid+n] = 0.5*acc - qzh[m] - qmuh[n], n<cvalid.
#define BM 64
#define BN 64
#define BK 64

template <int MODE>
__global__ __launch_bounds__(256) void gemm_bt(const u16* __restrict__ A,
                                               const u16* __restrict__ Bt,
                                               int N, int K, int nbn,
                                               u16* __restrict__ Cb,
                                               const float* __restrict__ muf,
                                               const float* __restrict__ zf,
                                               float* __restrict__ qmuh_w,
                                               float* __restrict__ qzh_w,
                                               const float* __restrict__ qzr,
                                               const float* __restrict__ qmr,
                                               float* __restrict__ So, int cvalid) {
    __shared__ char As[2][BM * BK * 2];   // 2 x 8 KiB
    __shared__ char Bs[2][BN * BK * 2];   // 2 x 8 KiB
    const int tid = threadIdx.x;
    const int bm = blockIdx.x / nbn, bn = blockIdx.x % nbn;
    const int m0 = bm * BM, n0 = bn * BN;
    const int lane = tid & 63, w = tid >> 6;
    const int wr = w >> 1, wc = w & 1;
    const int r16 = lane & 15, hk = lane >> 4;

    f32x4 acc[2][2] = {};
    const char* Ab = (const char*)A;
    const char* Bb = (const char*)Bt;

    // staging: chunk c = j*256+tid -> LDS row c>>3, 16B slot c&7 (linear dest,
    // wave-uniform base + lane*16). Global slot = slot ^ (row&7) so that
    // LDS[row][s] = G[row][s ^ (row&7)].
    auto stage = [&](int buf, int k0) {
        #pragma unroll
        for (int j = 0; j < 2; j++) {
            const int c = j * 256 + tid;
            const int row = c >> 3, slot = c & 7;
            const int goff = ((slot ^ (row & 7)) << 4);
            __builtin_amdgcn_global_load_lds(
                (gv_t*)(Ab + ((size_t)(m0 + row) * K + k0) * 2 + goff),
                (lv_t*)(As[buf] + c * 16), 16, 0, 0);
            __builtin_amdgcn_global_load_lds(
                (gv_t*)(Bb + ((size_t)(n0 + row) * K + k0) * 2 + goff),
                (lv_t*)(Bs[buf] + c * 16), 16, 0, 0);
        }
    };

    const int nt = K / BK;
    stage(0, 0);
    __syncthreads();                 // drain prologue loads
    int cur = 0;
    for (int t = 0; t < nt; ++t) {
        if (t + 1 < nt) stage(cur ^ 1, (t + 1) * BK);   // prefetch next tile
        bf16x8 a[2][2], b[2][2];
        #pragma unroll
        for (int mi = 0; mi < 2; mi++) {
            const int row = wr * 32 + mi * 16 + r16;
            #pragma unroll
            for (int kk = 0; kk < 2; kk++) {
                const int g = kk * 4 + hk;
                a[mi][kk] = *(const bf16x8*)(As[cur] + row * 128 + ((g ^ (row & 7)) << 4));
            }
        }
        #pragma unroll
        for (int ni = 0; ni < 2; ni++) {
            const int row = wc * 32 + ni * 16 + r16;
            #pragma unroll
            for (int kk = 0; kk < 2; kk++) {
                const int g = kk * 4 + hk;
                b[ni][kk] = *(const bf16x8*)(Bs[cur] + row * 128 + ((g ^ (row & 7)) << 4));
            }
        }
        #pragma unroll
        for (int kk = 0; kk < 2; kk++)
            #pragma unroll
            for (int mi = 0; mi < 2; mi++)
                #pragma unroll
                for (int ni = 0; ni < 2; ni++)
                    acc[mi][ni] = __builtin_amdgcn_mfma_f32_16x16x32_bf16(
                        a[mi][kk], b[ni][kk], acc[mi][ni], 0, 0, 0);
        __syncthreads();             // prefetch landed + all reads of cur done
        cur ^= 1;
    }

    // epilogue: C/D layout col=lane&15, row=(lane>>4)*4+r  [verified m89/m91]
    const int cr = hk * 4, cc = r16;
    if (MODE == 2) {
        #pragma unroll
        for (int mi = 0; mi < 2; mi++) {
            #pragma unroll
            for (int ni = 0; ni < 2; ni++) {
                const int gr = m0 + wr * 32 + mi * 16 + cr;
                const int gc = n0 + wc * 32 + ni * 16 + cc;
                if (gc < cvalid) {
                    float qm = qmr[gc];
                    #pragma unroll
                    for (int r = 0; r < 4; r++)
                        So[(size_t)(gr + r) * cvalid + gc] =
                            0.5f * acc[mi][ni][r] - qzr[gr + r] - qm;
                }
            }
        }
    } else {  // MODE 3: stacked [mu;z] x Q
        const bool isMu = (m0 < CP);                  // block-uniform (m0 % 64 == 0)
        const float* S = isMu ? muf : zf;
        float* dst = isMu ? qmuh_w : qzh_w;
        #pragma unroll
        for (int mi = 0; mi < 2; mi++) {
            const int gr0 = m0 + wr * 32 + mi * 16 + cr;
            const int rbase = isMu ? gr0 : gr0 - CP;
            #pragma unroll
            for (int r = 0; r < 4; r++) {
                const int row = rbase + r;
                float v = 0.f;
                #pragma unroll
                for (int ni = 0; ni < 2; ni++) {
                    const int gc = n0 + wc * 32 + ni * 16 + cc;
                    float av = acc[mi][ni][r];
                    v += av * S[(size_t)row * DD + gc];
                    if (isMu) Cb[(size_t)(gr0 + r) * N + gc] = f2bf(av);
                }
                #pragma unroll
                for (int m = 1; m < 16; m <<= 1) v += __shfl_xor(v, m);
                if (cc == 0) atomicAdd(dst + row, 0.25f * v);
            }
        }
    }
}

extern "C" void kernel_launch(void* const* d_in, const int* in_sizes, int n_in,
                              void* d_out, int out_size, void* d_ws, size_t ws_size,
                              hipStream_t stream) {
    const float* x  = (const float*)d_in[0];   // [N, D, S]
    const float* mu = (const float*)d_in[1];   // [C, D]
    const float* P  = (const float*)d_in[2];   // [D, D]
    float* out = (float*)d_out;                // [N, C]

    // workspace carve (~18.5 MB)
    char* w = (char*)d_ws;
    u16*   ab    = (u16*)w;    w += (size_t)(CP + NN) * DD * 2;  // [mu_bf ; z_bf]
    u16*   q_bf  = (u16*)w;    w += (size_t)DD * DD * 2;
    u16*   b_bf  = (u16*)w;    w += (size_t)CP * DD * 2;
    float* z_f32 = (float*)w;  w += (size_t)NN * DD * 4;
    float* qzh   = (float*)w;  w += (size_t)NN * 4;
    float* qmuh  = (float*)w;  /* CP*4 */

    u16* z_bf = ab + (size_t)CP * DD;

    // 1) fused pool (z f32+bf16) + prep (Q=bf16(P+P^T), mu->bf16, zero accums)
    pool_prep_k<<<POOL_BLOCKS + PREP_BLOCKS, 256, 0, stream>>>(
        x, P, mu, z_f32, z_bf, q_bf, ab, qzh, qmuh);
    // 2) stacked GEMM: [mu;z] x Q -> b_bf + qmuh/qzh atomics (zQ never stored)
    gemm_bt<3><<<((CP + NN) / BM) * (DD / BN), 256, 0, stream>>>(
        ab, q_bf, DD, DD, DD / BN, b_bf, mu, z_f32, qmuh, qzh,
        nullptr, nullptr, nullptr, 0);
    // 3) score GEMM: z x B^T, epilogue 0.5*acc - qzh[n] - qmuh[c] -> d_out
    gemm_bt<2><<<(NN / BM) * (CP / BN), 256, 0, stream>>>(
        z_bf, b_bf, CP, DD, CP / BN, nullptr, nullptr, nullptr, nullptr, nullptr,
        qzh, qmuh, out, CC);
}